// Round 9
// baseline (200.119 us; speedup 1.0000x reference)
//
#include <hip/hip_runtime.h>

typedef unsigned short u16;
typedef __attribute__((ext_vector_type(4))) float f32x4;
typedef __attribute__((ext_vector_type(8))) short s16x8;
typedef __attribute__((ext_vector_type(4))) unsigned short u16x4;
typedef __attribute__((ext_vector_type(2))) unsigned int u32x2;

#define S_ 2048
#define D_ 1024
#define H_ 16
#define KH 64
#define M_ 4096   // B*S
#define BH_ 32    // B*H

__device__ __forceinline__ float bf2f(u16 v) {
    union { unsigned int u; float f; } x; x.u = ((unsigned int)v) << 16; return x.f;
}
__device__ __forceinline__ u16 f2bf(float f) {
    union { float ff; unsigned int u; } x; x.ff = f;
    unsigned int r = x.u + 0x7fffu + ((x.u >> 16) & 1u);
    return (u16)(r >> 16);
}
__device__ __forceinline__ unsigned int cvt_pk_bf16(float lo, float hi) {
    unsigned int d;
    asm("v_cvt_pk_bf16_f32 %0, %1, %2" : "=v"(d) : "v"(lo), "v"(hi));
    return d;
}

// ---------------------------------------------------------------------------
// x (fp32, 4096x1024) -> xb (bf16)
// ---------------------------------------------------------------------------
__global__ void kcvt_x(const float* __restrict__ x, u16* __restrict__ xb) {
    const int i = (blockIdx.x * 256 + threadIdx.x) * 4;
    const float4 v = *(const float4*)&x[i];
    u16x4 o;
    o.x = f2bf(v.x); o.y = f2bf(v.y); o.z = f2bf(v.z); o.w = f2bf(v.w);
    *(u16x4*)&xb[i] = o;
}

// ---------------------------------------------------------------------------
// Weight pack (fp32 src -> bf16 dst):
//   mats 0-2: Wt[n*1024+d] = W[h=n>>6][d][k=n&63]  (n = h*64+k)
//   mat  3 : WtO[dc*1024+n] = W_O[n*1024+dc]
// ---------------------------------------------------------------------------
__global__ void ktrans_w(const float* __restrict__ WQ, const float* __restrict__ WK,
                         const float* __restrict__ WV, const float* __restrict__ WO,
                         u16* __restrict__ wt) {
    __shared__ u16 tile[64][65];
    const int mat = blockIdx.z;
    const float* src = (mat == 0) ? WQ : (mat == 1) ? WK : (mat == 2) ? WV : WO;
    u16* dst = wt + (size_t)mat * 1048576;
    const int a0 = blockIdx.x * 64, b0 = blockIdx.y * 64;
    const int t = threadIdx.x;
    const int bl = t & 63, ar = t >> 6;
    #pragma unroll
    for (int i = 0; i < 16; ++i) {
        int a = a0 + i * 4 + ar, b = b0 + bl;
        size_t sa = (mat < 3) ? (((size_t)(b >> 6)) << 16) + ((size_t)a << 6) + (b & 63)
                              : (size_t)a * 1024 + b;
        tile[i * 4 + ar][bl] = f2bf(src[sa]);
    }
    __syncthreads();
    #pragma unroll
    for (int i = 0; i < 16; ++i) {
        int bl2 = i * 4 + ar;
        dst[(size_t)(b0 + bl2) * 1024 + a0 + bl] = tile[bl][bl2];
    }
}

// ---------------------------------------------------------------------------
// QKV GEMM (R5-verified structure): 128x128 tile, BK=32, 4 waves, uniform
// swapped MFMA. z=0: Q, PRE-SCALED by 0.125*log2(e) (softmax scale folded in,
// bias included). z=1: K. z=2: scalar stores into Vt (BH,64,S).
// ---------------------------------------------------------------------------
__global__ __launch_bounds__(256)
void kgemm0(const u16* __restrict__ A, const u16* __restrict__ Wt,
            const float* __restrict__ b0p, const float* __restrict__ b1p,
            const float* __restrict__ b2p,
            u16* __restrict__ Qo, u16* __restrict__ Ko, u16* __restrict__ Vto) {
    __shared__ u16 As[2][128 * 32];
    __shared__ u16 Bs[2][128 * 32];
    const int t = threadIdx.x;
    const int l = t & 63, w = t >> 6;
    const int lq = l & 15, lg = l >> 4;
    const int wr = w >> 1, wc = w & 1;
    const int m0 = blockIdx.x * 128;
    const int n0 = blockIdx.y * 128;
    const int z = blockIdx.z;
    const u16* Bt = Wt + (size_t)z * 1048576;
    const float* bias = (z == 0) ? b0p : (z == 1) ? b1p : b2p;
    const float oscl = (z == 0) ? 0.18033688011112042f : 1.f;

    f32x4 acc[4][4] = {};

    auto stage = [&](int kt, int buf) {
        #pragma unroll
        for (int i = 0; i < 2; ++i) {
            int idx = t + i * 256;
            int row = idx >> 2, cc = idx & 3;
            const u16* ga = A + (size_t)(m0 + row) * 1024 + kt * 32 + cc * 8;
            const u16* gb = Bt + (size_t)(n0 + row) * 1024 + kt * 32 + cc * 8;
            __builtin_amdgcn_global_load_lds(
                (const __attribute__((address_space(1))) unsigned int*)ga,
                (__attribute__((address_space(3))) unsigned int*)(&As[buf][idx * 8]),
                16, 0, 0);
            __builtin_amdgcn_global_load_lds(
                (const __attribute__((address_space(1))) unsigned int*)gb,
                (__attribute__((address_space(3))) unsigned int*)(&Bs[buf][idx * 8]),
                16, 0, 0);
        }
    };

    stage(0, 0);
    __syncthreads();
    for (int kt = 0; kt < 32; ++kt) {
        const int cur = kt & 1;
        if (kt + 1 < 32) stage(kt + 1, cur ^ 1);
        s16x8 af[4], bf[4];
        #pragma unroll
        for (int m = 0; m < 4; ++m)
            af[m] = *(const s16x8*)&As[cur][(wr * 64 + m * 16 + lq) * 32 + lg * 8];
        #pragma unroll
        for (int n = 0; n < 4; ++n)
            bf[n] = *(const s16x8*)&Bs[cur][(wc * 64 + n * 16 + lq) * 32 + lg * 8];
        #pragma unroll
        for (int m = 0; m < 4; ++m)
            #pragma unroll
            for (int n = 0; n < 4; ++n)
                acc[m][n] = __builtin_amdgcn_mfma_f32_16x16x32_bf16(
                    bf[n], af[m], acc[m][n], 0, 0, 0);   // swapped: col frag-local
        __syncthreads();
    }

    #pragma unroll
    for (int n = 0; n < 4; ++n) {
        const int gcolb = n0 + wc * 64 + n * 16 + lg * 4;
        const float4 bv = *(const float4*)&bias[gcolb];
        const int h = gcolb >> 6, kk0 = gcolb & 63;
        #pragma unroll
        for (int m = 0; m < 4; ++m) {
            const int grow = m0 + wr * 64 + m * 16 + lq;
            const int b = grow >> 11, s = grow & 2047;
            const float v0 = (acc[m][n][0] + bv.x) * oscl;
            const float v1 = (acc[m][n][1] + bv.y) * oscl;
            const float v2 = (acc[m][n][2] + bv.z) * oscl;
            const float v3 = (acc[m][n][3] + bv.w) * oscl;
            if (z == 2) {
                u16* vb = Vto + ((size_t)((b * 16 + h) * 64 + kk0) * 2048 + s);
                vb[0] = f2bf(v0); vb[2048] = f2bf(v1);
                vb[4096] = f2bf(v2); vb[6144] = f2bf(v3);
            } else {
                u16* outp = (z == 0) ? Qo : Ko;
                u32x2 wp;
                wp.x = cvt_pk_bf16(v0, v1);
                wp.y = cvt_pk_bf16(v2, v3);
                *(u32x2*)&outp[((size_t)(b * 16 + h) * 2048 + s) * 64 + kk0] = wp;
            }
        }
    }
}

// ---------------------------------------------------------------------------
// Output GEMM: out = Z(4096x1024) * WtO^T + bO, fp32 out.
// 128x128 tile, BK=64 (32 MFMA/wave/barrier, 16 barriers), XOR-swizzled LDS
// (128B rows would be 16-way bank conflict), grid 256 = 1 block/CU with
// XCD-local decode (A 1MB + B 2MB per XCD fits L2).
// ---------------------------------------------------------------------------
__global__ __launch_bounds__(256)
void kgemm1(const u16* __restrict__ A, const u16* __restrict__ Bt,
            const float* __restrict__ bias, float* __restrict__ fo) {
    __shared__ u16 As[2][128 * 64];   // 16 KB each buf
    __shared__ u16 Bs[2][128 * 64];   // total 64 KB
    const int t = threadIdx.x;
    const int l = t & 63, w = t >> 6;
    const int lq = l & 15, lg = l >> 4;
    const int wr = w >> 1, wc = w & 1;

    const int lin = blockIdx.x;      // 0..255
    const int xcd = lin & 7;
    const int r = lin >> 3;          // 0..31
    const int mb = 4 * xcd + (r & 3);
    const int nb = r >> 2;           // 0..7
    const int m0 = mb * 128, n0 = nb * 128;

    f32x4 acc[4][4] = {};

    auto stage = [&](int kt, int buf) {
        #pragma unroll
        for (int i = 0; i < 4; ++i) {
            const int idx = t + i * 256;       // 1024 x 16B per tile
            const int row = idx >> 3;
            const int cg = (idx & 7) ^ (row & 7);   // pre-swizzled source chunk
            __builtin_amdgcn_global_load_lds(
                (const __attribute__((address_space(1))) unsigned int*)
                    (A + (size_t)(m0 + row) * 1024 + kt * 64 + cg * 8),
                (__attribute__((address_space(3))) unsigned int*)(&As[buf][idx * 8]),
                16, 0, 0);
            __builtin_amdgcn_global_load_lds(
                (const __attribute__((address_space(1))) unsigned int*)
                    (Bt + (size_t)(n0 + row) * 1024 + kt * 64 + cg * 8),
                (__attribute__((address_space(3))) unsigned int*)(&Bs[buf][idx * 8]),
                16, 0, 0);
        }
    };

    stage(0, 0);
    __syncthreads();
    for (int kt = 0; kt < 16; ++kt) {
        const int cur = kt & 1;
        if (kt + 1 < 16) stage(kt + 1, cur ^ 1);
        #pragma unroll
        for (int kk = 0; kk < 2; ++kk) {
            s16x8 af[4], bf[4];
            #pragma unroll
            for (int m = 0; m < 4; ++m) {
                const int row = wr * 64 + m * 16 + lq;
                const int c = ((kk * 4 + lg) ^ (lq & 7)) * 8;   // row&7 == lq&7
                af[m] = *(const s16x8*)&As[cur][row * 64 + c];
            }
            #pragma unroll
            for (int n = 0; n < 4; ++n) {
                const int row = wc * 64 + n * 16 + lq;
                const int c = ((kk * 4 + lg) ^ (lq & 7)) * 8;
                bf[n] = *(const s16x8*)&Bs[cur][row * 64 + c];
            }
            #pragma unroll
            for (int m = 0; m < 4; ++m)
                #pragma unroll
                for (int n = 0; n < 4; ++n)
                    acc[m][n] = __builtin_amdgcn_mfma_f32_16x16x32_bf16(
                        bf[n], af[m], acc[m][n], 0, 0, 0);
        }
        __syncthreads();
    }

    // swapped: lane holds 4 consecutive cols per acc -> float4 stores
    #pragma unroll
    for (int n = 0; n < 4; ++n) {
        const int gcolb = n0 + wc * 64 + n * 16 + lg * 4;
        const float4 bv = *(const float4*)&bias[gcolb];
        #pragma unroll
        for (int m = 0; m < 4; ++m) {
            const int grow = m0 + wr * 64 + m * 16 + lq;
            float4 o;
            o.x = acc[m][n][0] + bv.x;
            o.y = acc[m][n][1] + bv.y;
            o.z = acc[m][n][2] + bv.z;
            o.w = acc[m][n][3] + bv.w;
            *(float4*)&fo[(size_t)grow * 1024 + gcolb] = o;
        }
    }
}

// ---------------------------------------------------------------------------
// Flash attention: 1024 single-qt blocks, LPT + XCD-local. Q pre-scaled.
// Ones-row PV trick: V LDS tile has 80 rows; row 64 = bf16(1.0), 65..79 = 0.
// zacc[4] (the 5th PV fragment) accumulates the softmax denominator inside
// the MFMA with alpha rescaling applied by the same defer-max pass.
// ---------------------------------------------------------------------------
__global__ __launch_bounds__(256)
void kattn(const u16* __restrict__ Q, const u16* __restrict__ K,
           const u16* __restrict__ Vt, u16* __restrict__ Z) {
    __shared__ u16 Ks[2][64 * 64];
    __shared__ u16 Vs[2][80 * 64];
    __shared__ u16 Pl[4][16 * 72];
    const int t = threadIdx.x, l = t & 63, w = t >> 6;
    const int lq = l & 15, lg = l >> 4;

    // LPT + XCD-local decode: lin%8 = xcd; per XCD 4 bh x 32 qt, qt descending
    const int lin = blockIdx.x;          // 0..1023
    const int xcd = lin & 7;
    const int r = lin >> 3;              // 0..127
    const int qt = 31 - (r >> 2);
    const int bh = xcd + 8 * (r & 3);

    const size_t base = (size_t)bh * (S_ * KH);
    const u16* Qb = Q + base;
    const u16* Kb = K + base;
    const u16* Vb = Vt + base;
    const int b = bh >> 4, h = bh & 15;
    u16* Pw = &Pl[w][0];

    const int c0 = ((lg ^ (lq & 7)) * 8);
    const int c1 = c0 ^ 32;
    const float NINF = -__builtin_inff();

    // fill constant rows 64..79 of both V bufs (row 64 = 1.0, rest 0);
    // content is per-row constant -> swizzle-invariant.
    for (int i = t; i < 2048; i += 256) {
        const int bufi = i >> 10, rem = i & 1023;
        const int row = 64 + (rem >> 6), col = rem & 63;
        Vs[bufi][row * 64 + col] = (row == 64) ? (u16)0x3F80 : (u16)0;
    }

    auto stage = [&](int k0, int buf) {
        #pragma unroll
        for (int i = 0; i < 2; ++i) {
            const int idx2 = t + i * 256;
            const int row = idx2 >> 3;
            const int cg = (idx2 & 7) ^ (row & 7);
            __builtin_amdgcn_global_load_lds(
                (const __attribute__((address_space(1))) unsigned int*)
                    (Kb + (size_t)(k0 + row) * KH + cg * 8),
                (__attribute__((address_space(3))) unsigned int*)(&Ks[buf][idx2 * 8]),
                16, 0, 0);
            __builtin_amdgcn_global_load_lds(
                (const __attribute__((address_space(1))) unsigned int*)
                    (Vb + (size_t)row * S_ + k0 + cg * 8),
                (__attribute__((address_space(3))) unsigned int*)(&Vs[buf][idx2 * 8]),
                16, 0, 0);
        }
    };

    const int nt = qt + 1;
    const int qs = qt * 64 + w * 16;
    const int lim = w * 16 + lq;

    const s16x8 qf0 = *(const s16x8*)&Qb[(size_t)(qs + lq) * KH + lg * 8];
    const s16x8 qf1 = *(const s16x8*)&Qb[(size_t)(qs + lq) * KH + 32 + lg * 8];

    float mrow = NINF;
    f32x4 zacc[5] = {};   // [0..3] = z rows d 0..63; [4] = denominator row

    stage(0, 0);
    __syncthreads();

    for (int kt = 0; kt < nt; ++kt) {
        const int buf = kt & 1;
        if (kt + 1 < nt) stage((kt + 1) * 64, buf ^ 1);

        f32x4 sf[4] = {};
        __builtin_amdgcn_s_setprio(1);
        #pragma unroll
        for (int kf = 0; kf < 4; ++kf) {
            const int row = kf * 16 + lq;
            const s16x8 ka = *(const s16x8*)&Ks[buf][row * 64 + c0];
            const s16x8 kb = *(const s16x8*)&Ks[buf][row * 64 + c1];
            sf[kf] = __builtin_amdgcn_mfma_f32_16x16x32_bf16(ka, qf0, sf[kf], 0, 0, 0);
            sf[kf] = __builtin_amdgcn_mfma_f32_16x16x32_bf16(kb, qf1, sf[kf], 0, 0, 0);
        }
        __builtin_amdgcn_s_setprio(0);

        // sf already in log2 domain (Q pre-scaled). Causal mask on diag only.
        if (kt == qt) {
            #pragma unroll
            for (int kf = 0; kf < 4; ++kf)
                #pragma unroll
                for (int r2 = 0; r2 < 4; ++r2)
                    if ((kf * 16 + lg * 4 + r2) > lim) sf[kf][r2] = NINF;
        }

        float mk[4];
        #pragma unroll
        for (int kf = 0; kf < 4; ++kf)
            mk[kf] = fmaxf(fmaxf(sf[kf][0], sf[kf][1]), fmaxf(sf[kf][2], sf[kf][3]));
        float tmax = fmaxf(fmaxf(mk[0], mk[1]), fmaxf(mk[2], mk[3]));
        tmax = fmaxf(tmax, __shfl_xor(tmax, 16));
        tmax = fmaxf(tmax, __shfl_xor(tmax, 32));

        // defer-max rescale (covers denominator in zacc[4] automatically)
        if (!__all(tmax <= mrow + 8.f)) {
            const float nm = fmaxf(mrow, tmax);
            const float alpha = exp2f(mrow - nm);
            mrow = nm;
            #pragma unroll
            for (int nf = 0; nf < 5; ++nf)
                #pragma unroll
                for (int r2 = 0; r2 < 4; ++r2)
                    zacc[nf][r2] *= alpha;
        }

        // exp (in place); no sum tree -- MFMA ones-row does it
        #pragma unroll
        for (int kf = 0; kf < 4; ++kf)
            #pragma unroll
            for (int r2 = 0; r2 < 4; ++r2)
                sf[kf][r2] = exp2f(sf[kf][r2] - mrow);

        // pack P; lane's k-run is contiguous -> lands in A/B-frag layout
        #pragma unroll
        for (int kf = 0; kf < 4; ++kf) {
            u32x2 wp;
            wp.x = cvt_pk_bf16(sf[kf][0], sf[kf][1]);
            wp.y = cvt_pk_bf16(sf[kf][2], sf[kf][3]);
            *(u32x2*)&Pw[lq * 72 + kf * 16 + lg * 4] = wp;
        }
        const s16x8 pa0 = *(const s16x8*)&Pw[lq * 72 + lg * 8];
        const s16x8 pa1 = *(const s16x8*)&Pw[lq * 72 + 32 + lg * 8];

        __builtin_amdgcn_s_setprio(1);
        #pragma unroll
        for (int nf = 0; nf < 5; ++nf) {
            const int row = nf * 16 + lq;
            const s16x8 v0 = *(const s16x8*)&Vs[buf][row * 64 + c0];
            const s16x8 v1 = *(const s16x8*)&Vs[buf][row * 64 + c1];
            zacc[nf] = __builtin_amdgcn_mfma_f32_16x16x32_bf16(v0, pa0, zacc[nf], 0, 0, 0);
            zacc[nf] = __builtin_amdgcn_mfma_f32_16x16x32_bf16(v1, pa1, zacc[nf], 0, 0, 0);
        }
        __builtin_amdgcn_s_setprio(0);
        __syncthreads();
    }

    // denominator for q=lq sits at d=64 -> lane lq (lg=0), zacc[4][0]
    const float denom = __shfl(zacc[4][0], lq);
    const float rinv = 1.f / denom;
    const size_t zrow = (size_t)(b * S_ + qs + lq) * 1024 + h * 64;
    #pragma unroll
    for (int nf = 0; nf < 4; ++nf) {
        u32x2 wp;
        wp.x = cvt_pk_bf16(zacc[nf][0] * rinv, zacc[nf][1] * rinv);
        wp.y = cvt_pk_bf16(zacc[nf][2] * rinv, zacc[nf][3] * rinv);
        *(u32x2*)&Z[zrow + nf * 16 + lg * 4] = wp;
    }
}

// ---------------------------------------------------------------------------
extern "C" void kernel_launch(void* const* d_in, const int* in_sizes, int n_in,
                              void* d_out, int out_size, void* d_ws, size_t ws_size,
                              hipStream_t stream) {
    const float* x  = (const float*)d_in[0];
    const float* WQ = (const float*)d_in[1];
    const float* WK = (const float*)d_in[2];
    const float* WV = (const float*)d_in[3];
    const float* WO = (const float*)d_in[4];
    const float* bQ = (const float*)d_in[5];
    const float* bK = (const float*)d_in[6];
    const float* bV = (const float*)d_in[7];
    const float* bO = (const float*)d_in[8];
    float* out = (float*)d_out;

    u16* ws  = (u16*)d_ws;
    u16* xb  = ws;
    u16* wt  = xb + 4194304u;
    u16* Qb  = wt + 4194304u;
    u16* Kb  = Qb + 4194304u;
    u16* Vtb = Kb + 4194304u;
    u16* Zb  = Vtb + 4194304u;

    kcvt_x<<<dim3(4096), 256, 0, stream>>>(x, xb);
    ktrans_w<<<dim3(16, 16, 4), 256, 0, stream>>>(WQ, WK, WV, WO, wt);
    kgemm0<<<dim3(32, 8, 3), 256, 0, stream>>>(
        xb, wt, bQ, bK, bV, Qb, Kb, Vtb);
    kattn<<<dim3(1024), 256, 0, stream>>>(Qb, Kb, Vtb, Zb);
    kgemm1<<<dim3(256), 256, 0, stream>>>(
        Zb, wt + 3u * 1048576u, bO, out);
}